// Round 9
// baseline (174.473 us; speedup 1.0000x reference)
//
#include <hip/hip_runtime.h>

#define DIM 64
#define BIN_SHIFT 7                  // 128 nodes per bin
#define NODES_PER_BIN 128
#define MAX_BINS 1024                // ceil(100000/128)=782 <= 1024
#define BIN_CAP 2048                 // mean 1279, sigma ~36 -> 21-sigma margin
#define CHUNK_EDGES 2048             // edges per scatter block (R0-proven best)
#define SCATTER_THREADS 512          // wider block halves per-phase critical path
#define GEMM_ROWS 128                // rows per gemm block
#define FXSCALE 65536.0f             // fixed-point scale 2^16
#define FXINV (1.0f / 65536.0f)
#define FXBIAS 524288u               // 2^19 per-term bias (|v|<8 -> term >= 0)
#define MAGIC 12582912.0f            // 1.5*2^23 RNE float->int magic
#define MAGIC_I 0x4B400000u
#define AGG_STRIDE 9                 // u64 per node row: 8 used + 1 pad (quarter split)

// ws layout (256-aligned):
// gcur[MAX_BINS] | deg[N+1] | dinv[N+1] | pairs[nbins*BIN_CAP+64] | h[(N+1)*64] bf16
//
// Pipeline (1 memset + 4 dispatches):
//   memset gcur
//   K1 scatter: R0-proven bin scatter, 512 threads (halved serial phases)
//   K2 degree: per-bin histogram -> deg, dinv
//   K3 gemm: MFMA bf16 16x16x32, swizzled LDS frags, 25 KB -> 6 blocks/CU
//   K4 aggregate: feature-QUARTER split (4 blocks/bin), 9.2 KB LDS ->
//                 12 blocks/CU doubles outstanding gathers (Little's law)

using bf16x8 = __attribute__((ext_vector_type(8))) short;
using f32x4  = __attribute__((ext_vector_type(4))) float;

__device__ __forceinline__ unsigned short f2bf(float f) {
    unsigned u = __float_as_uint(f);
    u += 0x7fffu + ((u >> 16) & 1u);     // round-to-nearest-even
    return (unsigned short)(u >> 16);
}
__device__ __forceinline__ float bf2f(unsigned short u) {
    return __uint_as_float((unsigned)u << 16);
}

// K1: scatter packed (src<<7 | dst&127) into dst-bins.  512 threads, 4 edges
// per thread: every barrier-separated phase's critical path halves vs 256.
// One reservation atomic per (block,bin); contiguous write runs.
__global__ __launch_bounds__(SCATTER_THREADS) void bin_scatter_kernel(
    const void* __restrict__ ei, int* __restrict__ gcur,
    int* __restrict__ pairs, int E, int nbins) {
    __shared__ int h1[MAX_BINS];
    __shared__ int base[MAX_BINS];
    __shared__ int s_notz;
    int tid = threadIdx.x;
    if (tid == 0) s_notz = 0;
    for (int i = tid; i < nbins; i += SCATTER_THREADS) h1[i] = 0;
    __syncthreads();
    if (((const int*)ei)[2 * tid + 1] != 0) s_notz = 1;   // benign race (same value)
    __syncthreads();
    int is64 = (s_notz == 0);
    int chunk = blockIdx.x * CHUNK_EDGES;

    int ss[CHUNK_EDGES / SCATTER_THREADS], dd[CHUNK_EDGES / SCATTER_THREADS];
#pragma unroll
    for (int k = 0; k < CHUNK_EDGES / SCATTER_THREADS; ++k) {
        int i = chunk + k * SCATTER_THREADS + tid;
        if (i < E) {
            int s, d;
            if (is64) {
                s = (int)((const long long*)ei)[i];
                d = (int)((const long long*)ei)[(long long)i + E];
            } else {
                s = ((const int*)ei)[i];
                d = ((const int*)ei)[i + E];
            }
            ss[k] = s; dd[k] = d;
            atomicAdd(&h1[d >> BIN_SHIFT], 1);
        } else {
            dd[k] = -1;
        }
    }
    __syncthreads();
    for (int i = tid; i < nbins; i += SCATTER_THREADS) {
        int c = h1[i];
        base[i] = c ? (i * BIN_CAP + atomicAdd(&gcur[i], c)) : 0;
        h1[i] = 0;
    }
    __syncthreads();
#pragma unroll
    for (int k = 0; k < CHUNK_EDGES / SCATTER_THREADS; ++k) {
        if (dd[k] >= 0) {
            int bin = dd[k] >> BIN_SHIFT;
            int r = atomicAdd(&h1[bin], 1);
            int pos = base[bin] + r;
            if (pos < (bin + 1) * BIN_CAP)          // overflow guard (never expected)
                pairs[pos] = (ss[k] << BIN_SHIFT) | (dd[k] & (NODES_PER_BIN - 1));
        }
    }
}

// K2: per-bin degree histogram -> deg + dinv.
__global__ __launch_bounds__(256) void degree_kernel(const int* __restrict__ pairs,
                                                     const int* __restrict__ gcur,
                                                     int* __restrict__ deg,
                                                     float* __restrict__ dinv, int N) {
    __shared__ int sdeg[NODES_PER_BIN];
    int b = blockIdx.x;
    int tid = threadIdx.x;
    int base = b * BIN_CAP;
    int cnt = min(gcur[b], BIN_CAP);
    int node0 = b << BIN_SHIFT;
    int nn = min(NODES_PER_BIN, N - node0);
    if (tid < NODES_PER_BIN) sdeg[tid] = 0;
    __syncthreads();
    for (int i = tid; i < cnt; i += 256)
        atomicAdd(&sdeg[pairs[base + i] & (NODES_PER_BIN - 1)], 1);
    __syncthreads();
    if (tid < nn) {
        int d = sdeg[tid];
        deg[node0 + tid] = d;
        dinv[node0 + tid] = rsqrtf((float)(d + 1));   // +1 self-loop
    }
}

// K3: MFMA gemm (R7-proven).  h[r] = bf16( (x[r] @ W^T) * dinv[r] ).
// Block = 128 rows x 64 cols, 4 waves; 2 m-tiles x 4 n-tiles x 2 K-steps of
// mfma_f32_16x16x32_bf16.  LDS XOR-swizzle (byte ^= (row&7)<<4) breaks the
// stride-128B bank conflict on ds_read_b128 fragment loads.
__global__ __launch_bounds__(256) void gemm_kernel(const float* __restrict__ x,
                                                   const float* __restrict__ W,
                                                   const float* __restrict__ dinv,
                                                   unsigned short* __restrict__ h, int N) {
    __shared__ unsigned short Xs[GEMM_ROWS * 64];   // 16 KB, swizzled [row][k] bf16
    __shared__ unsigned short Ws[64 * 64];          // 8 KB,  swizzled [n][k]  bf16
    __shared__ float sdinv[GEMM_ROWS];
    int tid = threadIdx.x;
    int row0 = blockIdx.x * GEMM_ROWS;
    int nn = min(GEMM_ROWS, N - row0);

#pragma unroll
    for (int u = 0; u < 2; ++u) {
        int idx = u * 256 + tid;
        int c = idx >> 3, k0 = (idx & 7) * 8;
        float4 a = *(const float4*)&W[c * 64 + k0];
        float4 b = *(const float4*)&W[c * 64 + k0 + 4];
        bf16x8 v;
        v[0] = (short)f2bf(a.x); v[1] = (short)f2bf(a.y);
        v[2] = (short)f2bf(a.z); v[3] = (short)f2bf(a.w);
        v[4] = (short)f2bf(b.x); v[5] = (short)f2bf(b.y);
        v[6] = (short)f2bf(b.z); v[7] = (short)f2bf(b.w);
        int byteoff = c * 128 + ((k0 * 2) ^ ((c & 7) << 4));
        *(bf16x8*)((char*)Ws + byteoff) = v;
    }
    const float* xbase = x + (size_t)row0 * DIM;
#pragma unroll
    for (int u = 0; u < 4; ++u) {
        int idx = u * 256 + tid;
        int r = idx >> 3, k0 = (idx & 7) * 8;
        float4 a = make_float4(0.f, 0.f, 0.f, 0.f), b = a;
        if (r < nn) {
            a = *(const float4*)&xbase[r * DIM + k0];
            b = *(const float4*)&xbase[r * DIM + k0 + 4];
        }
        bf16x8 v;
        v[0] = (short)f2bf(a.x); v[1] = (short)f2bf(a.y);
        v[2] = (short)f2bf(a.z); v[3] = (short)f2bf(a.w);
        v[4] = (short)f2bf(b.x); v[5] = (short)f2bf(b.y);
        v[6] = (short)f2bf(b.z); v[7] = (short)f2bf(b.w);
        int byteoff = r * 128 + ((k0 * 2) ^ ((r & 7) << 4));
        *(bf16x8*)((char*)Xs + byteoff) = v;
    }
    if (tid < GEMM_ROWS) sdinv[tid] = (tid < nn) ? dinv[row0 + tid] : 0.0f;
    __syncthreads();

    int w = tid >> 6, l = tid & 63;
    int lm = l & 15, kg = l >> 4;
    f32x4 acc[2][4] = {};
#pragma unroll
    for (int ks = 0; ks < 2; ++ks) {
        int kbyte = ks * 64 + kg * 16;
        int r0g = 32 * w + lm;
        int r1g = 32 * w + 16 + lm;
        bf16x8 a0 = *(const bf16x8*)((const char*)Xs + r0g * 128 + (kbyte ^ ((r0g & 7) << 4)));
        bf16x8 a1 = *(const bf16x8*)((const char*)Xs + r1g * 128 + (kbyte ^ ((r1g & 7) << 4)));
#pragma unroll
        for (int nt = 0; nt < 4; ++nt) {
            int ng = nt * 16 + lm;
            bf16x8 bv = *(const bf16x8*)((const char*)Ws + ng * 128 + (kbyte ^ ((ng & 7) << 4)));
            acc[0][nt] = __builtin_amdgcn_mfma_f32_16x16x32_bf16(a0, bv, acc[0][nt], 0, 0, 0);
            acc[1][nt] = __builtin_amdgcn_mfma_f32_16x16x32_bf16(a1, bv, acc[1][nt], 0, 0, 0);
        }
    }
#pragma unroll
    for (int mt = 0; mt < 2; ++mt) {
#pragma unroll
        for (int j = 0; j < 4; ++j) {
            int rl = 32 * w + 16 * mt + (l >> 4) * 4 + j;
            if (rl < nn) {
                float dv = sdinv[rl];
                size_t rowoff = (size_t)(row0 + rl) * DIM;
#pragma unroll
                for (int nt = 0; nt < 4; ++nt)
                    h[rowoff + nt * 16 + lm] = f2bf(acc[mt][nt][j] * dv);
            }
        }
    }
}

// K4: feature-quarter aggregate.  Block = (bin, 16-feature quarter); 9.2 KB
// LDS -> grid 4*nbins = 3128 blocks = 12/CU -> 2x outstanding h-gathers vs
// the half-split (Little's law on the ~860ns L3 gather).  16 edges per wave
// step (4 lanes/edge), 2 u64 LDS atomics per edge-quarter.
__global__ __launch_bounds__(256) void aggregate_kernel(
    const unsigned short* __restrict__ h, const int* __restrict__ pairs,
    const int* __restrict__ gcur, const int* __restrict__ deg,
    const float* __restrict__ dinv, const float* __restrict__ bias,
    float* __restrict__ out, int N) {
    __shared__ unsigned long long acc[NODES_PER_BIN * AGG_STRIDE];   // 9216 B
    int blk = blockIdx.x;
    int b = blk >> 2;
    int f0 = (blk & 3) * 16;           // feature quarter offset
    int tid = threadIdx.x;
    int cnt = min(gcur[b], BIN_CAP);
    int node0 = b << BIN_SHIFT;
    int nn = min(NODES_PER_BIN, N - node0);

    for (int i = tid; i < NODES_PER_BIN * AGG_STRIDE; i += 256) acc[i] = 0ULL;
    __syncthreads();

    int wave = tid >> 6, lane = tid & 63;
    int g = lane >> 2;                 // edge slot 0..15
    int fq = lane & 3;                 // features f0 + 4*fq .. +3
    const int* pb = pairs + b * BIN_CAP;
    int dummy = N << BIN_SHIFT;        // row N load is garbage but gated off

    for (int j0 = 128 * wave; j0 < cnt; j0 += 512) {
        int pk[8]; bool vd[8];
#pragma unroll
        for (int u = 0; u < 8; ++u) {
            int e = j0 + 16 * u + g;
            vd[u] = (e < cnt);
            pk[u] = vd[u] ? pb[e] : dummy;
        }
        ushort4 r[8];
#pragma unroll
        for (int u = 0; u < 8; ++u)    // issue all gathers before use
            r[u] = *(const ushort4*)(h + (size_t)(pk[u] >> BIN_SHIFT) * DIM + f0 + 4 * fq);
#pragma unroll
        for (int u = 0; u < 8; ++u) {
            unsigned q0 = __float_as_uint(fmaf(bf2f(r[u].x), FXSCALE, MAGIC)) - (MAGIC_I - FXBIAS);
            unsigned q1 = __float_as_uint(fmaf(bf2f(r[u].y), FXSCALE, MAGIC)) - (MAGIC_I - FXBIAS);
            unsigned q2 = __float_as_uint(fmaf(bf2f(r[u].z), FXSCALE, MAGIC)) - (MAGIC_I - FXBIAS);
            unsigned q3 = __float_as_uint(fmaf(bf2f(r[u].w), FXSCALE, MAGIC)) - (MAGIC_I - FXBIAS);
            if (vd[u]) {
                unsigned long long* ar =
                    &acc[(pk[u] & (NODES_PER_BIN - 1)) * AGG_STRIDE + 2 * fq];
                atomicAdd(&ar[0], (unsigned long long)q0 | ((unsigned long long)q1 << 32));
                atomicAdd(&ar[1], (unsigned long long)q2 | ((unsigned long long)q3 << 32));
            }
        }
    }
    __syncthreads();

    // dword view: feature f (0..15) of node n at dword [n*18 + f]
    const int* accd = (const int*)acc;
    int featl = tid & 15;
    float bl = bias[f0 + featl];
    for (int n0 = (tid >> 4); n0 < nn; n0 += 16) {
        int gn = node0 + n0;
        int dgn = deg[gn];
        float di = dinv[gn];
        unsigned q = (unsigned)accd[n0 * (2 * AGG_STRIDE) + featl];
        int sfx = (int)(q - (unsigned)dgn * FXBIAS);        // remove per-term bias
        float sum = (float)sfx * FXINV;
        float self = bf2f(h[(size_t)gn * DIM + f0 + featl]); // pre-scaled by dinv[gn]
        out[(size_t)gn * DIM + f0 + featl] = (sum + self) * di + bl;
    }
}

extern "C" void kernel_launch(void* const* d_in, const int* in_sizes, int n_in,
                              void* d_out, int out_size, void* d_ws, size_t ws_size,
                              hipStream_t stream) {
    const float* x = (const float*)d_in[0];
    const void* ei = d_in[1];
    const float* W = (const float*)d_in[2];
    const float* b = (const float*)d_in[3];
    float* out = (float*)d_out;

    int N = in_sizes[0] / DIM;   // 100000
    int E = in_sizes[1] / 2;     // 1000000
    int nbins = (N + NODES_PER_BIN - 1) >> BIN_SHIFT;   // 782

    char* ws = (char*)d_ws;
    auto align256 = [](size_t v) { return (v + 255) & ~(size_t)255; };
    size_t off = 0;
    int* gcur = (int*)(ws + off);              off = align256(off + (size_t)MAX_BINS * 4);
    int* deg  = (int*)(ws + off);              off = align256(off + (size_t)(N + 1) * 4);
    float* dinv = (float*)(ws + off);          off = align256(off + (size_t)(N + 1) * 4);
    int* pairs = (int*)(ws + off);             off = align256(off + ((size_t)nbins * BIN_CAP + 64) * 4);
    unsigned short* h = (unsigned short*)(ws + off); off = align256(off + (size_t)(N + 1) * DIM * 2);

    int nchunks = (E + CHUNK_EDGES - 1) / CHUNK_EDGES;       // 489
    int gemmblocks = (N + GEMM_ROWS - 1) / GEMM_ROWS;        // 782

    hipMemsetAsync(gcur, 0, (size_t)MAX_BINS * 4, stream);
    bin_scatter_kernel<<<nchunks, SCATTER_THREADS, 0, stream>>>(ei, gcur, pairs, E, nbins);
    degree_kernel<<<nbins, 256, 0, stream>>>(pairs, gcur, deg, dinv, N);
    gemm_kernel<<<gemmblocks, 256, 0, stream>>>(x, W, dinv, h, N);
    aggregate_kernel<<<4 * nbins, 256, 0, stream>>>(h, pairs, gcur, deg, dinv, b, out, N);
}

// Round 10
// 134.612 us; speedup vs baseline: 1.2961x; 1.2961x over previous
//
#include <hip/hip_runtime.h>

#define DIM 64
#define BIN_SHIFT 7                  // 128 nodes per bin
#define NODES_PER_BIN 128
#define MAX_BINS 1024                // ceil(100000/128)=782 <= 1024
#define BIN_CAP 2048                 // mean 1279, sigma ~36 -> 21-sigma margin
#define CHUNK_EDGES 2048             // edges per scatter block (R0-proven best)
#define SCATTER_THREADS 512          // wider block halves per-phase critical path
#define GEMM_ROWS 128                // rows per gemm block
#define FXSCALE 65536.0f             // fixed-point scale 2^16
#define FXINV (1.0f / 65536.0f)
#define FXBIAS 524288u               // 2^19 per-term bias (|v|<8 -> term >= 0)
#define MAGIC 12582912.0f            // 1.5*2^23 RNE float->int magic
#define MAGIC_I 0x4B400000u
#define ACC_U64 33                   // u64 per node row: 32 used + 1 pad (full 64-feat)

// ws layout (256-aligned):
// gcur[MAX_BINS] | deg[N+1] | dinv[N+1] | pairs[nbins*BIN_CAP+64] | h[(N+1)*64] bf16
//
// Pipeline (1 memset + 4 dispatches):
//   memset gcur
//   K1 scatter: R0-proven bin scatter, 512 threads
//   K2 degree: per-bin histogram -> deg, dinv
//   K3 gemm: MFMA bf16 16x16x32, swizzled LDS frags
//   K4 aggregate: ONE block per bin (no feature split -> no fetch
//                 amplification; R9 measured 4x split = 4x FETCH = 207MB,
//                 L2-miss-path saturated at ~3 TB/s).  512 threads, 33 KB
//                 LDS -> 4 blocks x 8 waves = 32 waves/CU.

using bf16x8 = __attribute__((ext_vector_type(8))) short;
using f32x4  = __attribute__((ext_vector_type(4))) float;

__device__ __forceinline__ unsigned short f2bf(float f) {
    unsigned u = __float_as_uint(f);
    u += 0x7fffu + ((u >> 16) & 1u);     // round-to-nearest-even
    return (unsigned short)(u >> 16);
}
__device__ __forceinline__ float bf2f(unsigned short u) {
    return __uint_as_float((unsigned)u << 16);
}

// K1: scatter packed (src<<7 | dst&127) into dst-bins.  512 threads, 4 edges
// per thread.  One reservation atomic per (block,bin); contiguous write runs.
__global__ __launch_bounds__(SCATTER_THREADS) void bin_scatter_kernel(
    const void* __restrict__ ei, int* __restrict__ gcur,
    int* __restrict__ pairs, int E, int nbins) {
    __shared__ int h1[MAX_BINS];
    __shared__ int base[MAX_BINS];
    __shared__ int s_notz;
    int tid = threadIdx.x;
    if (tid == 0) s_notz = 0;
    for (int i = tid; i < nbins; i += SCATTER_THREADS) h1[i] = 0;
    __syncthreads();
    if (((const int*)ei)[2 * tid + 1] != 0) s_notz = 1;   // benign race (same value)
    __syncthreads();
    int is64 = (s_notz == 0);
    int chunk = blockIdx.x * CHUNK_EDGES;

    int ss[CHUNK_EDGES / SCATTER_THREADS], dd[CHUNK_EDGES / SCATTER_THREADS];
#pragma unroll
    for (int k = 0; k < CHUNK_EDGES / SCATTER_THREADS; ++k) {
        int i = chunk + k * SCATTER_THREADS + tid;
        if (i < E) {
            int s, d;
            if (is64) {
                s = (int)((const long long*)ei)[i];
                d = (int)((const long long*)ei)[(long long)i + E];
            } else {
                s = ((const int*)ei)[i];
                d = ((const int*)ei)[i + E];
            }
            ss[k] = s; dd[k] = d;
            atomicAdd(&h1[d >> BIN_SHIFT], 1);
        } else {
            dd[k] = -1;
        }
    }
    __syncthreads();
    for (int i = tid; i < nbins; i += SCATTER_THREADS) {
        int c = h1[i];
        base[i] = c ? (i * BIN_CAP + atomicAdd(&gcur[i], c)) : 0;
        h1[i] = 0;
    }
    __syncthreads();
#pragma unroll
    for (int k = 0; k < CHUNK_EDGES / SCATTER_THREADS; ++k) {
        if (dd[k] >= 0) {
            int bin = dd[k] >> BIN_SHIFT;
            int r = atomicAdd(&h1[bin], 1);
            int pos = base[bin] + r;
            if (pos < (bin + 1) * BIN_CAP)          // overflow guard (never expected)
                pairs[pos] = (ss[k] << BIN_SHIFT) | (dd[k] & (NODES_PER_BIN - 1));
        }
    }
}

// K2: per-bin degree histogram -> deg + dinv.
__global__ __launch_bounds__(256) void degree_kernel(const int* __restrict__ pairs,
                                                     const int* __restrict__ gcur,
                                                     int* __restrict__ deg,
                                                     float* __restrict__ dinv, int N) {
    __shared__ int sdeg[NODES_PER_BIN];
    int b = blockIdx.x;
    int tid = threadIdx.x;
    int base = b * BIN_CAP;
    int cnt = min(gcur[b], BIN_CAP);
    int node0 = b << BIN_SHIFT;
    int nn = min(NODES_PER_BIN, N - node0);
    if (tid < NODES_PER_BIN) sdeg[tid] = 0;
    __syncthreads();
    for (int i = tid; i < cnt; i += 256)
        atomicAdd(&sdeg[pairs[base + i] & (NODES_PER_BIN - 1)], 1);
    __syncthreads();
    if (tid < nn) {
        int d = sdeg[tid];
        deg[node0 + tid] = d;
        dinv[node0 + tid] = rsqrtf((float)(d + 1));   // +1 self-loop
    }
}

// K3: MFMA gemm (R7-proven).  h[r] = bf16( (x[r] @ W^T) * dinv[r] ).
// Block = 128 rows x 64 cols, 4 waves; 2 m-tiles x 4 n-tiles x 2 K-steps of
// mfma_f32_16x16x32_bf16.  LDS XOR-swizzle (byte ^= (row&7)<<4) breaks the
// stride-128B bank conflict on ds_read_b128 fragment loads.
__global__ __launch_bounds__(256) void gemm_kernel(const float* __restrict__ x,
                                                   const float* __restrict__ W,
                                                   const float* __restrict__ dinv,
                                                   unsigned short* __restrict__ h, int N) {
    __shared__ unsigned short Xs[GEMM_ROWS * 64];   // 16 KB, swizzled [row][k] bf16
    __shared__ unsigned short Ws[64 * 64];          // 8 KB,  swizzled [n][k]  bf16
    __shared__ float sdinv[GEMM_ROWS];
    int tid = threadIdx.x;
    int row0 = blockIdx.x * GEMM_ROWS;
    int nn = min(GEMM_ROWS, N - row0);

#pragma unroll
    for (int u = 0; u < 2; ++u) {
        int idx = u * 256 + tid;
        int c = idx >> 3, k0 = (idx & 7) * 8;
        float4 a = *(const float4*)&W[c * 64 + k0];
        float4 b = *(const float4*)&W[c * 64 + k0 + 4];
        bf16x8 v;
        v[0] = (short)f2bf(a.x); v[1] = (short)f2bf(a.y);
        v[2] = (short)f2bf(a.z); v[3] = (short)f2bf(a.w);
        v[4] = (short)f2bf(b.x); v[5] = (short)f2bf(b.y);
        v[6] = (short)f2bf(b.z); v[7] = (short)f2bf(b.w);
        int byteoff = c * 128 + ((k0 * 2) ^ ((c & 7) << 4));
        *(bf16x8*)((char*)Ws + byteoff) = v;
    }
    const float* xbase = x + (size_t)row0 * DIM;
#pragma unroll
    for (int u = 0; u < 4; ++u) {
        int idx = u * 256 + tid;
        int r = idx >> 3, k0 = (idx & 7) * 8;
        float4 a = make_float4(0.f, 0.f, 0.f, 0.f), b = a;
        if (r < nn) {
            a = *(const float4*)&xbase[r * DIM + k0];
            b = *(const float4*)&xbase[r * DIM + k0 + 4];
        }
        bf16x8 v;
        v[0] = (short)f2bf(a.x); v[1] = (short)f2bf(a.y);
        v[2] = (short)f2bf(a.z); v[3] = (short)f2bf(a.w);
        v[4] = (short)f2bf(b.x); v[5] = (short)f2bf(b.y);
        v[6] = (short)f2bf(b.z); v[7] = (short)f2bf(b.w);
        int byteoff = r * 128 + ((k0 * 2) ^ ((r & 7) << 4));
        *(bf16x8*)((char*)Xs + byteoff) = v;
    }
    if (tid < GEMM_ROWS) sdinv[tid] = (tid < nn) ? dinv[row0 + tid] : 0.0f;
    __syncthreads();

    int w = tid >> 6, l = tid & 63;
    int lm = l & 15, kg = l >> 4;
    f32x4 acc[2][4] = {};
#pragma unroll
    for (int ks = 0; ks < 2; ++ks) {
        int kbyte = ks * 64 + kg * 16;
        int r0g = 32 * w + lm;
        int r1g = 32 * w + 16 + lm;
        bf16x8 a0 = *(const bf16x8*)((const char*)Xs + r0g * 128 + (kbyte ^ ((r0g & 7) << 4)));
        bf16x8 a1 = *(const bf16x8*)((const char*)Xs + r1g * 128 + (kbyte ^ ((r1g & 7) << 4)));
#pragma unroll
        for (int nt = 0; nt < 4; ++nt) {
            int ng = nt * 16 + lm;
            bf16x8 bv = *(const bf16x8*)((const char*)Ws + ng * 128 + (kbyte ^ ((ng & 7) << 4)));
            acc[0][nt] = __builtin_amdgcn_mfma_f32_16x16x32_bf16(a0, bv, acc[0][nt], 0, 0, 0);
            acc[1][nt] = __builtin_amdgcn_mfma_f32_16x16x32_bf16(a1, bv, acc[1][nt], 0, 0, 0);
        }
    }
#pragma unroll
    for (int mt = 0; mt < 2; ++mt) {
#pragma unroll
        for (int j = 0; j < 4; ++j) {
            int rl = 32 * w + 16 * mt + (l >> 4) * 4 + j;
            if (rl < nn) {
                float dv = sdinv[rl];
                size_t rowoff = (size_t)(row0 + rl) * DIM;
#pragma unroll
                for (int nt = 0; nt < 4; ++nt)
                    h[rowoff + nt * 16 + lm] = f2bf(acc[mt][nt][j] * dv);
            }
        }
    }
}

// K4: full-feature aggregate, ONE block per bin (each h row fetched once ->
// ~52 MB unique traffic, no amplification).  512 threads = 8 waves; wave =
// 4 edge slots x 16 feature-lanes (lane covers 4 features, 2 u64 atomics per
// edge -> 0.5 LDS-atomic wave-instr/edge).  33 KB LDS -> 4 blocks/CU -> 32
// waves/CU full occupancy.
__global__ __launch_bounds__(512) void aggregate_kernel(
    const unsigned short* __restrict__ h, const int* __restrict__ pairs,
    const int* __restrict__ gcur, const int* __restrict__ deg,
    const float* __restrict__ dinv, const float* __restrict__ bias,
    float* __restrict__ out, int N) {
    __shared__ unsigned long long acc[NODES_PER_BIN * ACC_U64];   // 33792 B
    int b = blockIdx.x;
    int tid = threadIdx.x;
    int cnt = min(gcur[b], BIN_CAP);
    int node0 = b << BIN_SHIFT;
    int nn = min(NODES_PER_BIN, N - node0);

    for (int i = tid; i < NODES_PER_BIN * ACC_U64; i += 512) acc[i] = 0ULL;
    __syncthreads();

    int wave = tid >> 6, lane = tid & 63;
    int g = lane >> 4;                 // edge slot 0..3
    int fq = lane & 15;                // features 4*fq .. 4*fq+3
    const int* pb = pairs + b * BIN_CAP;
    int dummy = N << BIN_SHIFT;        // row N load is garbage but gated off

    for (int j0 = 32 * wave; j0 < cnt; j0 += 256) {
        int pk[8]; bool vd[8];
#pragma unroll
        for (int u = 0; u < 8; ++u) {
            int e = j0 + 4 * u + g;
            vd[u] = (e < cnt);
            pk[u] = vd[u] ? pb[e] : dummy;
        }
        ushort4 r[8];
#pragma unroll
        for (int u = 0; u < 8; ++u)    // issue all gathers before use
            r[u] = *(const ushort4*)(h + (size_t)(pk[u] >> BIN_SHIFT) * DIM + 4 * fq);
#pragma unroll
        for (int u = 0; u < 8; ++u) {
            unsigned q0 = __float_as_uint(fmaf(bf2f(r[u].x), FXSCALE, MAGIC)) - (MAGIC_I - FXBIAS);
            unsigned q1 = __float_as_uint(fmaf(bf2f(r[u].y), FXSCALE, MAGIC)) - (MAGIC_I - FXBIAS);
            unsigned q2 = __float_as_uint(fmaf(bf2f(r[u].z), FXSCALE, MAGIC)) - (MAGIC_I - FXBIAS);
            unsigned q3 = __float_as_uint(fmaf(bf2f(r[u].w), FXSCALE, MAGIC)) - (MAGIC_I - FXBIAS);
            if (vd[u]) {
                unsigned long long* ar =
                    &acc[(pk[u] & (NODES_PER_BIN - 1)) * ACC_U64 + 2 * fq];
                atomicAdd(&ar[0], (unsigned long long)q0 | ((unsigned long long)q1 << 32));
                atomicAdd(&ar[1], (unsigned long long)q2 | ((unsigned long long)q3 << 32));
            }
        }
    }
    __syncthreads();

    // dword view: feature f (0..63) of node n at dword [n*66 + f]
    const int* accd = (const int*)acc;
    float bl = bias[lane];
    for (int n0 = wave; n0 < nn; n0 += 8) {
        int gn = node0 + n0;
        int dgn = deg[gn];
        float di = dinv[gn];
        unsigned q = (unsigned)accd[n0 * (2 * ACC_U64) + lane];
        int sfx = (int)(q - (unsigned)dgn * FXBIAS);        // remove per-term bias
        float sum = (float)sfx * FXINV;
        float self = bf2f(h[(size_t)gn * DIM + lane]);      // pre-scaled by dinv[gn]
        out[(size_t)gn * DIM + lane] = (sum + self) * di + bl;
    }
}

extern "C" void kernel_launch(void* const* d_in, const int* in_sizes, int n_in,
                              void* d_out, int out_size, void* d_ws, size_t ws_size,
                              hipStream_t stream) {
    const float* x = (const float*)d_in[0];
    const void* ei = d_in[1];
    const float* W = (const float*)d_in[2];
    const float* b = (const float*)d_in[3];
    float* out = (float*)d_out;

    int N = in_sizes[0] / DIM;   // 100000
    int E = in_sizes[1] / 2;     // 1000000
    int nbins = (N + NODES_PER_BIN - 1) >> BIN_SHIFT;   // 782

    char* ws = (char*)d_ws;
    auto align256 = [](size_t v) { return (v + 255) & ~(size_t)255; };
    size_t off = 0;
    int* gcur = (int*)(ws + off);              off = align256(off + (size_t)MAX_BINS * 4);
    int* deg  = (int*)(ws + off);              off = align256(off + (size_t)(N + 1) * 4);
    float* dinv = (float*)(ws + off);          off = align256(off + (size_t)(N + 1) * 4);
    int* pairs = (int*)(ws + off);             off = align256(off + ((size_t)nbins * BIN_CAP + 64) * 4);
    unsigned short* h = (unsigned short*)(ws + off); off = align256(off + (size_t)(N + 1) * DIM * 2);

    int nchunks = (E + CHUNK_EDGES - 1) / CHUNK_EDGES;       // 489
    int gemmblocks = (N + GEMM_ROWS - 1) / GEMM_ROWS;        // 782

    hipMemsetAsync(gcur, 0, (size_t)MAX_BINS * 4, stream);
    bin_scatter_kernel<<<nchunks, SCATTER_THREADS, 0, stream>>>(ei, gcur, pairs, E, nbins);
    degree_kernel<<<nbins, 256, 0, stream>>>(pairs, gcur, deg, dinv, N);
    gemm_kernel<<<gemmblocks, 256, 0, stream>>>(x, W, dinv, h, N);
    aggregate_kernel<<<nbins, 512, 0, stream>>>(h, pairs, gcur, deg, dinv, b, out, N);
}

// Round 11
// 128.590 us; speedup vs baseline: 1.3568x; 1.0468x over previous
//
#include <hip/hip_runtime.h>

#define DIM 64
#define BIN_SHIFT 7                  // 128 nodes per bin
#define NODES_PER_BIN 128
#define MAX_BINS 1024                // ceil(100000/128)=782 <= 1024
#define BIN_CAP 2048                 // mean 1279, sigma ~36 -> 21-sigma margin
#define CHUNK_EDGES 4096             // edges per scatter block
#define SCATTER_THREADS 1024         // 4 edges/thread (width-scaling, R7->R10 trend)
#define GEMM_ROWS 128                // rows per gemm block == nodes per bin
#define FXSCALE 65536.0f             // fixed-point scale 2^16
#define FXINV (1.0f / 65536.0f)
#define FXBIAS 524288u               // 2^19 per-term bias (|v|<8 -> term >= 0)
#define MAGIC 12582912.0f            // 1.5*2^23 RNE float->int magic
#define MAGIC_I 0x4B400000u
#define ACC_U64 33                   // u64 per node row: 32 used + 1 pad

// ws layout (256-aligned):
// gcur[MAX_BINS] | deg[N+1] | dinv[N+1] | pairs[nbins*BIN_CAP+64] | h[(N+1)*64] bf16
//
// Pipeline (1 memset + 3 dispatches):
//   memset gcur (deg needs no zero: deg_gemm fully overwrites it)
//   K1 scatter: bin scatter, 1024 threads x 4096 edges (245 blocks ->
//               reservation queues halved vs 512/2048)
//   K2 deg_gemm: bin-degree histogram in LDS (tile b == bin b) -> sdinv ->
//               MFMA gemm, h = bf16((x @ W^T) * dinv[row]); writes deg/dinv
//               (25.6 KB LDS -> 6 blocks/CU; R5's 50 KB/3-blk mistake fixed)
//   K3 aggregate: one block per bin (no fetch amplification), 512 threads,
//               u64-packed biased fixed-point LDS atomics

using bf16x8 = __attribute__((ext_vector_type(8))) short;
using f32x4  = __attribute__((ext_vector_type(4))) float;

__device__ __forceinline__ unsigned short f2bf(float f) {
    unsigned u = __float_as_uint(f);
    u += 0x7fffu + ((u >> 16) & 1u);     // round-to-nearest-even
    return (unsigned short)(u >> 16);
}
__device__ __forceinline__ float bf2f(unsigned short u) {
    return __uint_as_float((unsigned)u << 16);
}

// K1: scatter packed (src<<7 | dst&127) into dst-bins.  1024 threads, 4
// edges/thread.  One reservation atomic per (block,bin); contiguous runs.
__global__ __launch_bounds__(SCATTER_THREADS) void bin_scatter_kernel(
    const void* __restrict__ ei, int* __restrict__ gcur,
    int* __restrict__ pairs, int E, int nbins) {
    __shared__ int h1[MAX_BINS];
    __shared__ int base[MAX_BINS];
    __shared__ int s_notz;
    int tid = threadIdx.x;
    if (tid == 0) s_notz = 0;
    for (int i = tid; i < nbins; i += SCATTER_THREADS) h1[i] = 0;
    __syncthreads();
    if (((const int*)ei)[2 * tid + 1] != 0) s_notz = 1;   // benign race (same value)
    __syncthreads();
    int is64 = (s_notz == 0);
    int chunk = blockIdx.x * CHUNK_EDGES;

    int ss[CHUNK_EDGES / SCATTER_THREADS], dd[CHUNK_EDGES / SCATTER_THREADS];
#pragma unroll
    for (int k = 0; k < CHUNK_EDGES / SCATTER_THREADS; ++k) {
        int i = chunk + k * SCATTER_THREADS + tid;
        if (i < E) {
            int s, d;
            if (is64) {
                s = (int)((const long long*)ei)[i];
                d = (int)((const long long*)ei)[(long long)i + E];
            } else {
                s = ((const int*)ei)[i];
                d = ((const int*)ei)[i + E];
            }
            ss[k] = s; dd[k] = d;
            atomicAdd(&h1[d >> BIN_SHIFT], 1);
        } else {
            dd[k] = -1;
        }
    }
    __syncthreads();
    for (int i = tid; i < nbins; i += SCATTER_THREADS) {
        int c = h1[i];
        base[i] = c ? (i * BIN_CAP + atomicAdd(&gcur[i], c)) : 0;
        h1[i] = 0;
    }
    __syncthreads();
#pragma unroll
    for (int k = 0; k < CHUNK_EDGES / SCATTER_THREADS; ++k) {
        if (dd[k] >= 0) {
            int bin = dd[k] >> BIN_SHIFT;
            int r = atomicAdd(&h1[bin], 1);
            int pos = base[bin] + r;
            if (pos < (bin + 1) * BIN_CAP)          // overflow guard (never expected)
                pairs[pos] = (ss[k] << BIN_SHIFT) | (dd[k] & (NODES_PER_BIN - 1));
        }
    }
}

// K2: fused degree + MFMA gemm.  Tile b == bin b: bin b's pairs are exactly
// the in-edges of its 128 nodes, so the degree histogram lives in LDS and
// feeds the epilogue's dinv scale directly; deg/dinv written for K3.
// 25.6 KB LDS -> 6 blocks/CU (R5's 50 KB variant was the occupancy mistake).
__global__ __launch_bounds__(256) void deg_gemm_kernel(
    const float* __restrict__ x, const float* __restrict__ W,
    const int* __restrict__ pairs, const int* __restrict__ gcur,
    int* __restrict__ deg, float* __restrict__ dinv,
    unsigned short* __restrict__ h, int N) {
    __shared__ unsigned short Xs[GEMM_ROWS * 64];   // 16 KB, swizzled [row][k] bf16
    __shared__ unsigned short Ws[64 * 64];          // 8 KB,  swizzled [n][k]  bf16
    __shared__ int sdeg[NODES_PER_BIN];
    __shared__ float sdinv[NODES_PER_BIN];
    int tid = threadIdx.x;
    int b = blockIdx.x;
    int row0 = b << BIN_SHIFT;
    int nn = min(GEMM_ROWS, N - row0);
    int cntb = min(gcur[b], BIN_CAP);

    if (tid < NODES_PER_BIN) sdeg[tid] = 0;
    // stage W (64x64 fp32 -> bf16), 2 x 16B writes per thread
#pragma unroll
    for (int u = 0; u < 2; ++u) {
        int idx = u * 256 + tid;
        int c = idx >> 3, k0 = (idx & 7) * 8;
        float4 a = *(const float4*)&W[c * 64 + k0];
        float4 bb = *(const float4*)&W[c * 64 + k0 + 4];
        bf16x8 v;
        v[0] = (short)f2bf(a.x); v[1] = (short)f2bf(a.y);
        v[2] = (short)f2bf(a.z); v[3] = (short)f2bf(a.w);
        v[4] = (short)f2bf(bb.x); v[5] = (short)f2bf(bb.y);
        v[6] = (short)f2bf(bb.z); v[7] = (short)f2bf(bb.w);
        int byteoff = c * 128 + ((k0 * 2) ^ ((c & 7) << 4));
        *(bf16x8*)((char*)Ws + byteoff) = v;
    }
    // stage X (128x64 fp32 -> bf16), 4 x 16B writes per thread
    const float* xbase = x + (size_t)row0 * DIM;
#pragma unroll
    for (int u = 0; u < 4; ++u) {
        int idx = u * 256 + tid;
        int r = idx >> 3, k0 = (idx & 7) * 8;
        float4 a = make_float4(0.f, 0.f, 0.f, 0.f), bb = a;
        if (r < nn) {
            a = *(const float4*)&xbase[r * DIM + k0];
            bb = *(const float4*)&xbase[r * DIM + k0 + 4];
        }
        bf16x8 v;
        v[0] = (short)f2bf(a.x); v[1] = (short)f2bf(a.y);
        v[2] = (short)f2bf(a.z); v[3] = (short)f2bf(a.w);
        v[4] = (short)f2bf(bb.x); v[5] = (short)f2bf(bb.y);
        v[6] = (short)f2bf(bb.z); v[7] = (short)f2bf(bb.w);
        int byteoff = r * 128 + ((k0 * 2) ^ ((r & 7) << 4));
        *(bf16x8*)((char*)Xs + byteoff) = v;
    }
    __syncthreads();                 // sdeg zeroed (staging needs no barrier yet)
    const int* pb = pairs + b * BIN_CAP;
    for (int i = tid; i < cntb; i += 256)
        atomicAdd(&sdeg[pb[i] & (NODES_PER_BIN - 1)], 1);
    __syncthreads();                 // hist done; Ws/Xs visible too
    if (tid < NODES_PER_BIN) {
        int d = sdeg[tid];
        float dv = rsqrtf((float)(d + 1));     // +1 self-loop
        sdinv[tid] = dv;
        if (tid < nn) {
            deg[row0 + tid] = d;
            dinv[row0 + tid] = dv;
        }
    }
    __syncthreads();                 // sdinv visible

    int w = tid >> 6, l = tid & 63;
    int lm = l & 15, kg = l >> 4;
    f32x4 acc[2][4] = {};
#pragma unroll
    for (int ks = 0; ks < 2; ++ks) {
        int kbyte = ks * 64 + kg * 16;
        int r0g = 32 * w + lm;
        int r1g = 32 * w + 16 + lm;
        bf16x8 a0 = *(const bf16x8*)((const char*)Xs + r0g * 128 + (kbyte ^ ((r0g & 7) << 4)));
        bf16x8 a1 = *(const bf16x8*)((const char*)Xs + r1g * 128 + (kbyte ^ ((r1g & 7) << 4)));
#pragma unroll
        for (int nt = 0; nt < 4; ++nt) {
            int ng = nt * 16 + lm;
            bf16x8 bv = *(const bf16x8*)((const char*)Ws + ng * 128 + (kbyte ^ ((ng & 7) << 4)));
            acc[0][nt] = __builtin_amdgcn_mfma_f32_16x16x32_bf16(a0, bv, acc[0][nt], 0, 0, 0);
            acc[1][nt] = __builtin_amdgcn_mfma_f32_16x16x32_bf16(a1, bv, acc[1][nt], 0, 0, 0);
        }
    }
    // epilogue: D row = (l>>4)*4 + j, col = l&15 within each 16x16 tile
#pragma unroll
    for (int mt = 0; mt < 2; ++mt) {
#pragma unroll
        for (int j = 0; j < 4; ++j) {
            int rl = 32 * w + 16 * mt + (l >> 4) * 4 + j;
            if (rl < nn) {
                float dv = sdinv[rl];
                size_t rowoff = (size_t)(row0 + rl) * DIM;
#pragma unroll
                for (int nt = 0; nt < 4; ++nt)
                    h[rowoff + nt * 16 + lm] = f2bf(acc[mt][nt][j] * dv);
            }
        }
    }
}

// K3: full-feature aggregate, ONE block per bin (each h row fetched once ->
// no amplification; R9 measured 4x split = 4x FETCH, L2-miss path saturated).
// 512 threads = 8 waves; wave = 4 edge slots x 16 feature-lanes; 2 u64 LDS
// atomics per edge (0.5 wave-instr/edge).  33 KB LDS -> 4 blocks/CU.
__global__ __launch_bounds__(512) void aggregate_kernel(
    const unsigned short* __restrict__ h, const int* __restrict__ pairs,
    const int* __restrict__ gcur, const int* __restrict__ deg,
    const float* __restrict__ dinv, const float* __restrict__ bias,
    float* __restrict__ out, int N) {
    __shared__ unsigned long long acc[NODES_PER_BIN * ACC_U64];   // 33792 B
    int b = blockIdx.x;
    int tid = threadIdx.x;
    int cnt = min(gcur[b], BIN_CAP);
    int node0 = b << BIN_SHIFT;
    int nn = min(NODES_PER_BIN, N - node0);

    for (int i = tid; i < NODES_PER_BIN * ACC_U64; i += 512) acc[i] = 0ULL;
    __syncthreads();

    int wave = tid >> 6, lane = tid & 63;
    int g = lane >> 4;                 // edge slot 0..3
    int fq = lane & 15;                // features 4*fq .. 4*fq+3
    const int* pb = pairs + b * BIN_CAP;
    int dummy = N << BIN_SHIFT;        // row N load is garbage but gated off

    for (int j0 = 32 * wave; j0 < cnt; j0 += 256) {
        int pk[8]; bool vd[8];
#pragma unroll
        for (int u = 0; u < 8; ++u) {
            int e = j0 + 4 * u + g;
            vd[u] = (e < cnt);
            pk[u] = vd[u] ? pb[e] : dummy;
        }
        ushort4 r[8];
#pragma unroll
        for (int u = 0; u < 8; ++u)    // issue all gathers before use
            r[u] = *(const ushort4*)(h + (size_t)(pk[u] >> BIN_SHIFT) * DIM + 4 * fq);
#pragma unroll
        for (int u = 0; u < 8; ++u) {
            unsigned q0 = __float_as_uint(fmaf(bf2f(r[u].x), FXSCALE, MAGIC)) - (MAGIC_I - FXBIAS);
            unsigned q1 = __float_as_uint(fmaf(bf2f(r[u].y), FXSCALE, MAGIC)) - (MAGIC_I - FXBIAS);
            unsigned q2 = __float_as_uint(fmaf(bf2f(r[u].z), FXSCALE, MAGIC)) - (MAGIC_I - FXBIAS);
            unsigned q3 = __float_as_uint(fmaf(bf2f(r[u].w), FXSCALE, MAGIC)) - (MAGIC_I - FXBIAS);
            if (vd[u]) {
                unsigned long long* ar =
                    &acc[(pk[u] & (NODES_PER_BIN - 1)) * ACC_U64 + 2 * fq];
                atomicAdd(&ar[0], (unsigned long long)q0 | ((unsigned long long)q1 << 32));
                atomicAdd(&ar[1], (unsigned long long)q2 | ((unsigned long long)q3 << 32));
            }
        }
    }
    __syncthreads();

    // dword view: feature f (0..63) of node n at dword [n*66 + f]
    const int* accd = (const int*)acc;
    float bl = bias[lane];
    for (int n0 = wave; n0 < nn; n0 += 8) {
        int gn = node0 + n0;
        int dgn = deg[gn];
        float di = dinv[gn];
        unsigned q = (unsigned)accd[n0 * (2 * ACC_U64) + lane];
        int sfx = (int)(q - (unsigned)dgn * FXBIAS);        // remove per-term bias
        float sum = (float)sfx * FXINV;
        float self = bf2f(h[(size_t)gn * DIM + lane]);      // pre-scaled by dinv[gn]
        out[(size_t)gn * DIM + lane] = (sum + self) * di + bl;
    }
}

extern "C" void kernel_launch(void* const* d_in, const int* in_sizes, int n_in,
                              void* d_out, int out_size, void* d_ws, size_t ws_size,
                              hipStream_t stream) {
    const float* x = (const float*)d_in[0];
    const void* ei = d_in[1];
    const float* W = (const float*)d_in[2];
    const float* b = (const float*)d_in[3];
    float* out = (float*)d_out;

    int N = in_sizes[0] / DIM;   // 100000
    int E = in_sizes[1] / 2;     // 1000000
    int nbins = (N + NODES_PER_BIN - 1) >> BIN_SHIFT;   // 782

    char* ws = (char*)d_ws;
    auto align256 = [](size_t v) { return (v + 255) & ~(size_t)255; };
    size_t off = 0;
    int* gcur = (int*)(ws + off);              off = align256(off + (size_t)MAX_BINS * 4);
    int* deg  = (int*)(ws + off);              off = align256(off + (size_t)(N + 1) * 4);
    float* dinv = (float*)(ws + off);          off = align256(off + (size_t)(N + 1) * 4);
    int* pairs = (int*)(ws + off);             off = align256(off + ((size_t)nbins * BIN_CAP + 64) * 4);
    unsigned short* h = (unsigned short*)(ws + off); off = align256(off + (size_t)(N + 1) * DIM * 2);

    int nchunks = (E + CHUNK_EDGES - 1) / CHUNK_EDGES;       // 245
    int gemmblocks = nbins;                                  // tile b == bin b

    hipMemsetAsync(gcur, 0, (size_t)MAX_BINS * 4, stream);
    bin_scatter_kernel<<<nchunks, SCATTER_THREADS, 0, stream>>>(ei, gcur, pairs, E, nbins);
    deg_gemm_kernel<<<gemmblocks, 256, 0, stream>>>(x, W, pairs, gcur, deg, dinv, h, N);
    aggregate_kernel<<<nbins, 512, 0, stream>>>(h, pairs, gcur, deg, dinv, b, out, N);
}